// Round 2
// baseline (252.151 us; speedup 1.0000x reference)
//
#include <hip/hip_runtime.h>

#define BATCH 64
#define CH 31
#define HF 28
#define WF 28
#define NCELL 784   // 28*28
#define NCLS 21
#define BGCLS 20
#define SORTN 1024  // next pow2 >= NCELL
#define NW 13       // u64 words covering 784 bits
#define TRI_WORDS 5776  // sum over rows i of (NW - (i>>6))

// dynamic LDS layout (bytes):
//   [0,      46208)  mask  u64[5776]   (aliased: sort keys u64[1024] live here)
//   [46208,  58752)  sbox  float4[784] (sorted, class-offset boxes)
//   [58752,  61888)  sarea float[784]
//   [61888,  63456)  orig  ushort[784]
#define SMEM_BYTES 63456

// ---------------------------------------------------------------------------
// Kernel 1: per-cell decode (unchanged from round 1 — not a bottleneck).
// ---------------------------------------------------------------------------
__global__ void decode_kernel(const float* __restrict__ feat,
                              const int* __restrict__ hofp,
                              const int* __restrict__ wofp,
                              float* __restrict__ out,
                              float4* __restrict__ ws_box,
                              float* __restrict__ ws_score)
{
    int gid = blockIdx.x * blockDim.x + threadIdx.x;
    if (gid >= BATCH * NCELL) return;
    int b = gid / NCELL;
    int n = gid - b * NCELL;

    const float* base = feat + (size_t)b * CH * NCELL + n;
    float x[CH];
#pragma unroll
    for (int c = 0; c < CH; ++c) x[c] = base[(size_t)c * NCELL];

    float c0 = x[4], c1 = x[9];
    int carg = (c1 > c0) ? 1 : 0;
    float cmax = fmaxf(c0, c1);

    float m = x[10];
#pragma unroll
    for (int k = 1; k < NCLS; ++k) m = fmaxf(m, x[10 + k]);
    float e[NCLS];
    float sum = 0.0f;
#pragma unroll
    for (int k = 0; k < NCLS; ++k) { e[k] = expf(x[10 + k] - m); sum += e[k]; }

    float best = -INFINITY;
    int cat = 0;
#pragma unroll
    for (int k = 0; k < NCLS; ++k) {
        float cp = cmax * (e[k] / sum);
        if (cp > best) { best = cp; cat = k; }
    }

    float rx = carg ? x[5] : x[0];
    float ry = carg ? x[6] : x[1];
    float rw = carg ? x[7] : x[2];
    float rh = carg ? x[8] : x[3];
    rx = 1.0f / (1.0f + expf(-rx));
    ry = 1.0f / (1.0f + expf(-ry));
    rw = 1.0f / (1.0f + expf(-rw));
    rh = 1.0f / (1.0f + expf(-rh));

    float w_ori = (float)(*wofp), h_ori = (float)(*hofp);
    float sw = w_ori / (float)WF, sh = h_ori / (float)HF;
    float col = (float)(n % WF), row = (float)(n / WF);
    float cx = (rx + col) * sw;
    float cy = (ry + row) * sh;
    float bw = rw * w_ori;
    float bh = rh * h_ori;
    float x1 = cx - bw * 0.5f, y1 = cy - bh * 0.5f;
    float x2 = cx + bw * 0.5f, y2 = cy + bh * 0.5f;

    float* o = out + (size_t)gid * 7;
    o[0] = x1; o[1] = y1; o[2] = x2; o[3] = y2;
    o[4] = best; o[5] = (float)cat;

    float off = (float)cat * 4096.0f;
    ws_box[gid] = make_float4(x1 + off, y1 + off, x2 + off, y2 + off);
    ws_score[gid] = (cat != BGCLS) ? best : -INFINITY;
}

// ---------------------------------------------------------------------------
// Kernel 2: fused sort + suppression-bitmask + wave-synchronous greedy scan.
// One block per batch image, 1024 threads.
// ---------------------------------------------------------------------------
__global__ __launch_bounds__(SORTN)
void nms_kernel(const float4* __restrict__ ws_box,
                const float* __restrict__ ws_score,
                float* __restrict__ out)
{
    extern __shared__ char smem[];
    unsigned long long* mask = (unsigned long long*)smem;       // & sort keys
    float4*  sbox  = (float4*)(smem + 46208);
    float*   sarea = (float*)(smem + 58752);
    unsigned short* orig = (unsigned short*)(smem + 61888);
    __shared__ unsigned long long remv0[NW];

    int b = blockIdx.x;
    int t = threadIdx.x;

    // ---- phase 1: build sort keys (stable descending argsort) ----
    unsigned long long key = 0ull;   // pads sort last (all real keys > 0)
    if (t < NCELL) {
        float sc = ws_score[(size_t)b * NCELL + t];
        unsigned u = __float_as_uint(sc);
        u = (u & 0x80000000u) ? ~u : (u | 0x80000000u);
        key = ((unsigned long long)u << 32) |
              (unsigned long long)(0xFFFFFFFFu - (unsigned)t);
    }
    mask[t] = key;
    __syncthreads();

    // ---- phase 2: bitonic sort, descending ----
    for (int k = 2; k <= SORTN; k <<= 1) {
        for (int j = k >> 1; j > 0; j >>= 1) {
            int ixj = t ^ j;
            if (ixj > t) {
                unsigned long long a = mask[t], c2 = mask[ixj];
                bool descSeg = ((t & k) == 0);
                if (descSeg ? (a < c2) : (a > c2)) { mask[t] = c2; mask[ixj] = a; }
            }
            __syncthreads();
        }
    }

    // ---- phase 3: gather sorted boxes/areas; initial removed-bits = invalid ----
    bool inval = false;
    if (t < NCELL) {
        unsigned long long kk = mask[t];
        int o = (int)(0xFFFFFFFFu - (unsigned)(kk & 0xFFFFFFFFull));
        orig[t] = (unsigned short)o;
        float4 bb = ws_box[(size_t)b * NCELL + o];
        sbox[t] = bb;
        sarea[t] = fmaxf(bb.z - bb.x, 0.f) * fmaxf(bb.w - bb.y, 0.f);
        inval = ((kk >> 32) == 0x007FFFFFull);   // score was -inf
    }
    unsigned long long bal = __ballot(t < NCELL && inval);
    if ((t & 63) == 0 && (t >> 6) < NW) remv0[t >> 6] = bal;
    __syncthreads();   // keys fully consumed; mask region reusable

    // ---- phase 4: build triangular suppression bitmask ----
    // word (i, w) holds bits j in [w*64, w*64+64) : set iff j>i && iou>thr.
    for (int task = t; task < NCELL * NW; task += SORTN) {
        int i = task / NW;
        int w = task - i * NW;
        int q = i >> 6;
        if (w < q) continue;
        int r = i & 63;
        int base = NW * i - 32 * q * (q - 1) - r * q + (w - q);
        float4 bi = sbox[i];
        float ai = sarea[i];
        unsigned long long m = 0ull;
#pragma unroll 8
        for (int s = 0; s < 64; ++s) {
            int bit = (s + w * 5) & 63;        // rotate start: spread LDS banks
            int j = (w << 6) + bit;
            if (j > i && j < NCELL) {
                float4 bj = sbox[j];
                float xx1 = fmaxf(bi.x, bj.x), yy1 = fmaxf(bi.y, bj.y);
                float xx2 = fminf(bi.z, bj.z), yy2 = fminf(bi.w, bj.w);
                float inter = fmaxf(xx2 - xx1, 0.f) * fmaxf(yy2 - yy1, 0.f);
                float uni = ai + sarea[j] - inter;
                if (inter / fmaxf(uni, 1e-9f) > 0.5f) m |= (1ull << bit);
            }
        }
        mask[base] = m;
    }
    __syncthreads();

    // ---- phase 5: wave-synchronous greedy scan (wave 0 only, no barriers) ----
    // lane l holds remv word l; per item: uniform readlane test + masked OR of
    // the prefetched row. A bit is final once the scan reaches it.
    if (t < 64) {
        int lane = t;
        unsigned rL = 0u, rH = 0u;
        if (lane < NW) {
            unsigned long long r0 = remv0[lane];
            rL = (unsigned)r0; rH = (unsigned)(r0 >> 32);
        }
        int sbase = 0;
        for (int w = 0; w < NW; ++w) {
            int rows = (w < 12) ? 64 : (NCELL - 768);   // 64 or 16
            int L = NW - w;
            bool active = (lane >= w) && (lane < NW);
            const unsigned long long* rowp = mask + sbase + (active ? (lane - w) : 0);
            unsigned long long bf0 = rowp[0];
            unsigned long long bf1 = rowp[1 * L];
            unsigned long long bf2 = rowp[2 * L];
            unsigned long long bf3 = rowp[3 * L];

#define SCAN_STEP(BUF, BIT)                                                    \
            {                                                                  \
                int bit_ = (BIT);                                              \
                unsigned selv = (bit_ & 32) ? rH : rL;                         \
                unsigned sw_ = __builtin_amdgcn_readlane(selv, w);             \
                if (!((sw_ >> (bit_ & 31)) & 1u)) {                            \
                    unsigned long long m_ = active ? BUF : 0ull;               \
                    rL |= (unsigned)m_; rH |= (unsigned)(m_ >> 32);            \
                }                                                              \
                BUF = (bit_ + 4 < rows) ? rowp[(bit_ + 4) * L] : 0ull;         \
            }

            for (int bb_ = 0; bb_ < rows; bb_ += 4) {
                SCAN_STEP(bf0, bb_ + 0)
                SCAN_STEP(bf1, bb_ + 1)
                SCAN_STEP(bf2, bb_ + 2)
                SCAN_STEP(bf3, bb_ + 3)
            }
#undef SCAN_STEP
            sbase += rows * L;
        }
        if (lane < NW)
            remv0[lane] = ((unsigned long long)rH << 32) | (unsigned long long)rL;
    }
    __syncthreads();

    // ---- phase 6: scatter keep flags ----
    if (t < NCELL) {
        int o = orig[t];
        bool kept = !((remv0[t >> 6] >> (t & 63)) & 1ull);
        out[((size_t)b * NCELL + o) * 7 + 6] = kept ? 1.0f : 0.0f;
    }
}

extern "C" void kernel_launch(void* const* d_in, const int* in_sizes, int n_in,
                              void* d_out, int out_size, void* d_ws, size_t ws_size,
                              hipStream_t stream) {
    const float* feat = (const float*)d_in[0];
    const int* h_ori  = (const int*)d_in[1];
    const int* w_ori  = (const int*)d_in[2];
    float* out = (float*)d_out;

    float4* ws_box   = (float4*)d_ws;
    float*  ws_score = (float*)((char*)d_ws + sizeof(float4) * BATCH * NCELL);

    int total = BATCH * NCELL;
    decode_kernel<<<(total + 255) / 256, 256, 0, stream>>>(
        feat, h_ori, w_ori, out, ws_box, ws_score);
    nms_kernel<<<BATCH, SORTN, SMEM_BYTES, stream>>>(ws_box, ws_score, out);
}

// Round 3
// 144.240 us; speedup vs baseline: 1.7481x; 1.7481x over previous
//
#include <hip/hip_runtime.h>

#define BATCH 64
#define CH 31
#define HF 28
#define WF 28
#define NCELL 784   // 28*28
#define NCLS 21
#define BGCLS 20
#define SORTN 1024  // next pow2 >= NCELL
#define NW 13       // u64 words covering 784 bits
#define TRI_WORDS 5776  // sum over rows i of (NW - (i>>6))

// dynamic LDS layout (bytes):
//   [0,      46208)  mask  u64[5776]   (aliased: sort keys u64[1024] live here)
//   [46208,  58752)  sbox  float4[784] (sorted, class-offset boxes)
//   [58752,  60320)  orig  ushort[784]
#define SMEM_BYTES 60320

__device__ __forceinline__ float bcast_f(float v, int l) {
    return __int_as_float(__builtin_amdgcn_readlane(__float_as_int(v), l));
}

// ---------------------------------------------------------------------------
// Kernel 1: per-cell decode (unchanged — not a bottleneck).
// ---------------------------------------------------------------------------
__global__ void decode_kernel(const float* __restrict__ feat,
                              const int* __restrict__ hofp,
                              const int* __restrict__ wofp,
                              float* __restrict__ out,
                              float4* __restrict__ ws_box,
                              float* __restrict__ ws_score)
{
    int gid = blockIdx.x * blockDim.x + threadIdx.x;
    if (gid >= BATCH * NCELL) return;
    int b = gid / NCELL;
    int n = gid - b * NCELL;

    const float* base = feat + (size_t)b * CH * NCELL + n;
    float x[CH];
#pragma unroll
    for (int c = 0; c < CH; ++c) x[c] = base[(size_t)c * NCELL];

    float c0 = x[4], c1 = x[9];
    int carg = (c1 > c0) ? 1 : 0;
    float cmax = fmaxf(c0, c1);

    float m = x[10];
#pragma unroll
    for (int k = 1; k < NCLS; ++k) m = fmaxf(m, x[10 + k]);
    float e[NCLS];
    float sum = 0.0f;
#pragma unroll
    for (int k = 0; k < NCLS; ++k) { e[k] = expf(x[10 + k] - m); sum += e[k]; }

    float best = -INFINITY;
    int cat = 0;
#pragma unroll
    for (int k = 0; k < NCLS; ++k) {
        float cp = cmax * (e[k] / sum);
        if (cp > best) { best = cp; cat = k; }
    }

    float rx = carg ? x[5] : x[0];
    float ry = carg ? x[6] : x[1];
    float rw = carg ? x[7] : x[2];
    float rh = carg ? x[8] : x[3];
    rx = 1.0f / (1.0f + expf(-rx));
    ry = 1.0f / (1.0f + expf(-ry));
    rw = 1.0f / (1.0f + expf(-rw));
    rh = 1.0f / (1.0f + expf(-rh));

    float w_ori = (float)(*wofp), h_ori = (float)(*hofp);
    float sw = w_ori / (float)WF, sh = h_ori / (float)HF;
    float col = (float)(n % WF), row = (float)(n / WF);
    float cx = (rx + col) * sw;
    float cy = (ry + row) * sh;
    float bw = rw * w_ori;
    float bh = rh * h_ori;
    float x1 = cx - bw * 0.5f, y1 = cy - bh * 0.5f;
    float x2 = cx + bw * 0.5f, y2 = cy + bh * 0.5f;

    float* o = out + (size_t)gid * 7;
    o[0] = x1; o[1] = y1; o[2] = x2; o[3] = y2;
    o[4] = best; o[5] = (float)cat;

    float off = (float)cat * 4096.0f;
    ws_box[gid] = make_float4(x1 + off, y1 + off, x2 + off, y2 + off);
    ws_score[gid] = (cat != BGCLS) ? best : -INFINITY;
}

// ---------------------------------------------------------------------------
// Kernel 2: sort + broadcast-IoU suppression bitmask + wave-synchronous scan.
// One block per batch image, 1024 threads.
// ---------------------------------------------------------------------------
__global__ __launch_bounds__(SORTN)
void nms_kernel(const float4* __restrict__ ws_box,
                const float* __restrict__ ws_score,
                float* __restrict__ out)
{
    extern __shared__ char smem[];
    unsigned long long* mask = (unsigned long long*)smem;       // & sort keys
    float4*  sbox = (float4*)(smem + 46208);
    unsigned short* orig = (unsigned short*)(smem + 58752);
    __shared__ unsigned long long remv0[NW];

    int b = blockIdx.x;
    int t = threadIdx.x;

    // ---- phase 1: build sort keys (stable descending argsort) ----
    unsigned long long key = 0ull;   // pads sort last (all real keys > 0)
    if (t < NCELL) {
        float sc = ws_score[(size_t)b * NCELL + t];
        unsigned u = __float_as_uint(sc);
        u = (u & 0x80000000u) ? ~u : (u | 0x80000000u);
        key = ((unsigned long long)u << 32) |
              (unsigned long long)(0xFFFFFFFFu - (unsigned)t);
    }
    mask[t] = key;
    __syncthreads();

    // ---- phase 2: bitonic sort, descending ----
    // Steps with j<64 exchange only within one wave's 64-key segment: a full
    // block barrier is needed only when the NEXT step communicates cross-wave.
    for (int k = 2; k <= SORTN; k <<= 1) {
        for (int j = k >> 1; j > 0; j >>= 1) {
            int ixj = t ^ j;
            if (ixj > t) {
                unsigned long long a = mask[t], c2 = mask[ixj];
                bool descSeg = ((t & k) == 0);
                if (descSeg ? (a < c2) : (a > c2)) { mask[t] = c2; mask[ixj] = a; }
            }
            // next step's stride: j/2 if j>1, else next stage starts at k.
            int nextj = (j > 1) ? (j >> 1) : k;
            if (j < 64 && nextj < 64) {
                asm volatile("s_waitcnt lgkmcnt(0)" ::: "memory");
            } else {
                __syncthreads();
            }
        }
    }

    // ---- phase 3: gather sorted boxes; initial removed-bits = invalid ----
    bool inval = false;
    if (t < NCELL) {
        unsigned long long kk = mask[t];
        int o = (int)(0xFFFFFFFFu - (unsigned)(kk & 0xFFFFFFFFull));
        orig[t] = (unsigned short)o;
        sbox[t] = ws_box[(size_t)b * NCELL + o];
        inval = ((kk >> 32) == 0x007FFFFFull);   // score was -inf
    }
    unsigned long long bal = __ballot(t < NCELL && inval);
    if ((t & 63) == 0 && (t >> 6) < NW) remv0[t >> 6] = bal;
    __syncthreads();   // keys fully consumed; mask region reusable

    // ---- phase 4: build triangular suppression bitmask, broadcast IoU ----
    // 91 wave-tasks (ib, w), w >= ib. Lane = row i = ib*64+lane. Column boxes
    // loaded once into per-lane regs, broadcast per step via v_readlane.
    {
        int wave = t >> 6;
        int lane = t & 63;
        for (int task = wave; task < 91; task += 16) {
            int ib = 0, acc = 0;
            while (acc + (NW - ib) <= task) { acc += NW - ib; ++ib; }
            int w = ib + (task - acc);

            int i = (ib << 6) + lane;
            bool rowok = i < NCELL;
            float4 bi = sbox[rowok ? i : (NCELL - 1)];
            float ai = fmaxf(bi.z - bi.x, 0.f) * fmaxf(bi.w - bi.y, 0.f);

            int jb = (w << 6) + lane;
            float4 cj = sbox[jb < NCELL ? jb : (NCELL - 1)];
            float caj = fmaxf(cj.z - cj.x, 0.f) * fmaxf(cj.w - cj.y, 0.f);

            int jlim = NCELL - (w << 6);       // uniform; 64 except last word
            unsigned mL = 0u, mH = 0u;
#pragma unroll
            for (int s = 0; s < 64; ++s) {
                if (s >= jlim) break;          // uniform branch
                float jx  = bcast_f(cj.x, s);
                float jy  = bcast_f(cj.y, s);
                float jz  = bcast_f(cj.z, s);
                float jw2 = bcast_f(cj.w, s);
                float aj  = bcast_f(caj, s);
                float xx1 = fmaxf(bi.x, jx), yy1 = fmaxf(bi.y, jy);
                float xx2 = fminf(bi.z, jz), yy2 = fminf(bi.w, jw2);
                float iw = fmaxf(xx2 - xx1, 0.f), ih = fmaxf(yy2 - yy1, 0.f);
                float inter = iw * ih;
                float uni = ai + aj - inter;
                bool cond = inter > 0.5f * fmaxf(uni, 1e-9f);
                if (s < 32) mL |= cond ? (1u << s) : 0u;
                else        mH |= cond ? (1u << (s - 32)) : 0u;
            }
            unsigned long long m = ((unsigned long long)mH << 32) |
                                   (unsigned long long)mL;
            // diagonal word: only bits j>i, i.e. s>lane
            if (w == ib) m &= (lane >= 63) ? 0ull : (~0ull << (lane + 1));
            if (rowok) {
                int idx = 832 * ib - 32 * ib * (ib - 1) + (w - ib)
                        + lane * (NW - ib);
                mask[idx] = m;
            }
        }
    }
    __syncthreads();

    // ---- phase 5: wave-synchronous greedy scan (wave 0 only, no barriers) ----
    if (t < 64) {
        int lane = t;
        unsigned rL = 0u, rH = 0u;
        if (lane < NW) {
            unsigned long long r0 = remv0[lane];
            rL = (unsigned)r0; rH = (unsigned)(r0 >> 32);
        }
        int sbase = 0;
        for (int w = 0; w < NW; ++w) {
            int rows = (w < 12) ? 64 : (NCELL - 768);   // 64 or 16
            int L = NW - w;
            bool active = (lane >= w) && (lane < NW);
            const unsigned long long* rowp = mask + sbase + (active ? (lane - w) : 0);
            unsigned long long bf0 = rowp[0];
            unsigned long long bf1 = rowp[1 * L];
            unsigned long long bf2 = rowp[2 * L];
            unsigned long long bf3 = rowp[3 * L];

#define SCAN_STEP(BUF, BIT)                                                    \
            {                                                                  \
                int bit_ = (BIT);                                              \
                unsigned selv = (bit_ & 32) ? rH : rL;                         \
                unsigned sw_ = __builtin_amdgcn_readlane(selv, w);             \
                if (!((sw_ >> (bit_ & 31)) & 1u)) {                            \
                    unsigned long long m_ = active ? BUF : 0ull;               \
                    rL |= (unsigned)m_; rH |= (unsigned)(m_ >> 32);            \
                }                                                              \
                BUF = (bit_ + 4 < rows) ? rowp[(bit_ + 4) * L] : 0ull;         \
            }

            for (int bb_ = 0; bb_ < rows; bb_ += 4) {
                SCAN_STEP(bf0, bb_ + 0)
                SCAN_STEP(bf1, bb_ + 1)
                SCAN_STEP(bf2, bb_ + 2)
                SCAN_STEP(bf3, bb_ + 3)
            }
#undef SCAN_STEP
            sbase += rows * L;
        }
        if (lane < NW)
            remv0[lane] = ((unsigned long long)rH << 32) | (unsigned long long)rL;
    }
    __syncthreads();

    // ---- phase 6: scatter keep flags ----
    if (t < NCELL) {
        int o = orig[t];
        bool kept = !((remv0[t >> 6] >> (t & 63)) & 1ull);
        out[((size_t)b * NCELL + o) * 7 + 6] = kept ? 1.0f : 0.0f;
    }
}

extern "C" void kernel_launch(void* const* d_in, const int* in_sizes, int n_in,
                              void* d_out, int out_size, void* d_ws, size_t ws_size,
                              hipStream_t stream) {
    const float* feat = (const float*)d_in[0];
    const int* h_ori  = (const int*)d_in[1];
    const int* w_ori  = (const int*)d_in[2];
    float* out = (float*)d_out;

    float4* ws_box   = (float4*)d_ws;
    float*  ws_score = (float*)((char*)d_ws + sizeof(float4) * BATCH * NCELL);

    int total = BATCH * NCELL;
    decode_kernel<<<(total + 255) / 256, 256, 0, stream>>>(
        feat, h_ori, w_ori, out, ws_box, ws_score);
    nms_kernel<<<BATCH, SORTN, SMEM_BYTES, stream>>>(ws_box, ws_score, out);
}

// Round 4
// 32.324 us; speedup vs baseline: 7.8007x; 4.4623x over previous
//
#include <hip/hip_runtime.h>

#define BATCH 64
#define CH 31
#define HF 28
#define WF 28
#define NCELL 784   // 28*28
#define NCLS 21
#define BGCLS 20
#define CAP 128     // per-class bucket capacity (P(n>128) ~ 1e-38)
#define NMS_THR 0.5f

__device__ __forceinline__ float bcast_f(float v, int l) {
    return __int_as_float(__builtin_amdgcn_readlane(__float_as_int(v), l));
}
__device__ __forceinline__ unsigned long long shfl_xor_u64(unsigned long long v, int j) {
    int lo = __shfl_xor((int)(unsigned)(v & 0xFFFFFFFFull), j, 64);
    int hi = __shfl_xor((int)(unsigned)(v >> 32), j, 64);
    return ((unsigned long long)(unsigned)hi << 32) | (unsigned)lo;
}

// compare-exchange with partner lane^J; UP=true -> ascending pair
#define CEX0(VAR, J, UP) { unsigned long long p_ = shfl_xor_u64(VAR, (J));     \
    bool tm_ = (((lane & (J)) == 0) == (UP));                                  \
    VAR = ((VAR < p_) == tm_) ? VAR : p_; }

// ---------------------------------------------------------------------------
// One block per image: decode -> LDS class buckets -> per-wave per-class
// stable sort (in-register bitonic) -> wave-synchronous greedy NMS.
// Exactness: cross-class IoU == 0 (class offset 4096), so global greedy NMS
// decomposes exactly into per-class greedy NMS in (score desc, cell asc) order.
// ---------------------------------------------------------------------------
__global__ __launch_bounds__(1024)
void yolo_fused(const float* __restrict__ feat,
                const int* __restrict__ hofp,
                const int* __restrict__ wofp,
                float* __restrict__ out)
{
    __shared__ float4 sbox[NCELL];                    // class-offset boxes by cell
    __shared__ unsigned long long lkeys[NCLS - 1][CAP];
    __shared__ int lcount[NCLS - 1];

    const int b = blockIdx.x;
    const int t = threadIdx.x;

    if (t < NCLS - 1) lcount[t] = 0;
    {
        unsigned long long* lk = &lkeys[0][0];
        for (int i = t; i < (NCLS - 1) * CAP; i += 1024) lk[i] = ~0ull;
    }
    __syncthreads();

    // ---- decode cell t ----
    if (t < NCELL) {
        const float* base = feat + (size_t)b * CH * NCELL + t;
        float x[CH];
#pragma unroll
        for (int c = 0; c < CH; ++c) x[c] = base[(size_t)c * NCELL];

        float c0 = x[4], c1 = x[9];
        int carg = (c1 > c0) ? 1 : 0;
        float cmax = fmaxf(c0, c1);

        float m = x[10];
#pragma unroll
        for (int k = 1; k < NCLS; ++k) m = fmaxf(m, x[10 + k]);
        float e[NCLS];
        float sum = 0.0f;
#pragma unroll
        for (int k = 0; k < NCLS; ++k) { e[k] = expf(x[10 + k] - m); sum += e[k]; }

        float best = -INFINITY;
        int cat = 0;
#pragma unroll
        for (int k = 0; k < NCLS; ++k) {
            float cp = cmax * (e[k] / sum);
            if (cp > best) { best = cp; cat = k; }
        }

        float rx = carg ? x[5] : x[0];
        float ry = carg ? x[6] : x[1];
        float rw = carg ? x[7] : x[2];
        float rh = carg ? x[8] : x[3];
        rx = 1.0f / (1.0f + expf(-rx));
        ry = 1.0f / (1.0f + expf(-ry));
        rw = 1.0f / (1.0f + expf(-rw));
        rh = 1.0f / (1.0f + expf(-rh));

        float w_ori = (float)(*wofp), h_ori = (float)(*hofp);
        float sw = w_ori / (float)WF, sh = h_ori / (float)HF;
        float col = (float)(t % WF), row = (float)(t / WF);
        float cx = (rx + col) * sw;
        float cy = (ry + row) * sh;
        float bw = rw * w_ori;
        float bh = rh * h_ori;
        float x1 = cx - bw * 0.5f, y1 = cy - bh * 0.5f;
        float x2 = cx + bw * 0.5f, y2 = cy + bh * 0.5f;

        float* o = out + ((size_t)b * NCELL + t) * 7;
        o[0] = x1; o[1] = y1; o[2] = x2; o[3] = y2;
        o[4] = best; o[5] = (float)cat; o[6] = 0.0f;

        float off = (float)cat * 4096.0f;   // keep offset: bitwise parity w/ ref
        sbox[t] = make_float4(x1 + off, y1 + off, x2 + off, y2 + off);

        if (cat != BGCLS) {
            unsigned u = __float_as_uint(best);
            u = (u & 0x80000000u) ? ~u : (u | 0x80000000u);   // orderable asc
            unsigned long long key =
                ((unsigned long long)(~u) << 10) | (unsigned)t; // score desc, cell asc
            int slot = atomicAdd(&lcount[cat], 1);
            if (slot < CAP) lkeys[cat][slot] = key;
        }
    }
    __syncthreads();

    // ---- per-wave, per-class sort + greedy ----
    const int wave = t >> 6, lane = t & 63;

    for (int c = wave; c < NCLS - 1; c += 16) {
        int n = lcount[c]; if (n > CAP) n = CAP;
        if (n == 0) continue;

        unsigned long long k0 = lkeys[c][lane];
        unsigned long long k1 = lkeys[c][64 + lane];
        bool two = (n > 64);

        if (!two) {
            // 64-wide bitonic, ascending
#pragma unroll
            for (int k = 2; k <= 64; k <<= 1) {
                bool up = ((lane & k) == 0);   // k=64 -> true
#pragma unroll
                for (int j = k >> 1; j >= 1; j >>= 1) CEX0(k0, j, up)
            }
        } else {
            // 128-wide bitonic across (k0 = e<64, k1 = e>=64), ascending
#pragma unroll
            for (int k = 2; k <= 32; k <<= 1) {
                bool up = ((lane & k) == 0);
#pragma unroll
                for (int j = k >> 1; j >= 1; j >>= 1) { CEX0(k0, j, up) CEX0(k1, j, up) }
            }
#pragma unroll
            for (int j = 32; j >= 1; j >>= 1) { CEX0(k0, j, true) CEX0(k1, j, false) }
            {
                unsigned long long mn = (k0 < k1) ? k0 : k1;
                unsigned long long mx = (k0 < k1) ? k1 : k0;
                k0 = mn; k1 = mx;
            }
#pragma unroll
            for (int j = 32; j >= 1; j >>= 1) { CEX0(k0, j, true) CEX0(k1, j, true) }
        }

        int cell0 = (int)(k0 & 1023ull);
        int cell1 = (int)(k1 & 1023ull);
        bool ok0 = (lane < n);
        bool ok1 = (64 + lane) < n;

        float4 B0 = sbox[ok0 ? cell0 : 0];
        float a0 = fmaxf(B0.z - B0.x, 0.f) * fmaxf(B0.w - B0.y, 0.f);
        float4 B1 = make_float4(0.f, 0.f, 0.f, 0.f);
        float a1 = 0.f;
        if (two) {
            B1 = sbox[ok1 ? cell1 : 0];
            a1 = fmaxf(B1.z - B1.x, 0.f) * fmaxf(B1.w - B1.y, 0.f);
        }

        unsigned long long keep0 = (n >= 64) ? ~0ull : ((1ull << n) - 1);
        unsigned long long keep1 = two ? ((n >= 128) ? ~0ull : ((1ull << (n - 64)) - 1))
                                       : 0ull;

        // chunk-0 suppressors (i = 0..min(n,64)-1), skipping already-removed
        unsigned long long rem = keep0;
        while (rem) {
            int i = __builtin_ctzll(rem);
            rem &= rem - 1;
            float ix1 = bcast_f(B0.x, i), iy1 = bcast_f(B0.y, i);
            float ix2 = bcast_f(B0.z, i), iy2 = bcast_f(B0.w, i);
            float ia  = bcast_f(a0, i);
            {
                float xx1 = fmaxf(ix1, B0.x), yy1 = fmaxf(iy1, B0.y);
                float xx2 = fminf(ix2, B0.z), yy2 = fminf(iy2, B0.w);
                float inter = fmaxf(xx2 - xx1, 0.f) * fmaxf(yy2 - yy1, 0.f);
                float uni = ia + a0 - inter;
                bool s = (inter / fmaxf(uni, 1e-9f)) > NMS_THR;
                unsigned long long mm = __ballot(s) & keep0;
                mm &= (i < 63) ? (~0ull << (i + 1)) : 0ull;
                keep0 &= ~mm; rem &= ~mm;
            }
            if (two) {
                float xx1 = fmaxf(ix1, B1.x), yy1 = fmaxf(iy1, B1.y);
                float xx2 = fminf(ix2, B1.z), yy2 = fminf(iy2, B1.w);
                float inter = fmaxf(xx2 - xx1, 0.f) * fmaxf(yy2 - yy1, 0.f);
                float uni = ia + a1 - inter;
                bool s = (inter / fmaxf(uni, 1e-9f)) > NMS_THR;
                keep1 &= ~(__ballot(s) & keep1);
            }
        }
        // chunk-1 suppressors
        if (two) {
            unsigned long long rem1 = keep1;
            while (rem1) {
                int i = __builtin_ctzll(rem1);
                rem1 &= rem1 - 1;
                float ix1 = bcast_f(B1.x, i), iy1 = bcast_f(B1.y, i);
                float ix2 = bcast_f(B1.z, i), iy2 = bcast_f(B1.w, i);
                float ia  = bcast_f(a1, i);
                float xx1 = fmaxf(ix1, B1.x), yy1 = fmaxf(iy1, B1.y);
                float xx2 = fminf(ix2, B1.z), yy2 = fminf(iy2, B1.w);
                float inter = fmaxf(xx2 - xx1, 0.f) * fmaxf(yy2 - yy1, 0.f);
                float uni = ia + a1 - inter;
                bool s = (inter / fmaxf(uni, 1e-9f)) > NMS_THR;
                unsigned long long mm = __ballot(s) & keep1;
                mm &= (i < 63) ? (~0ull << (i + 1)) : 0ull;
                keep1 &= ~mm; rem1 &= ~mm;
            }
        }

        if (ok0 && ((keep0 >> lane) & 1ull))
            out[((size_t)b * NCELL + cell0) * 7 + 6] = 1.0f;
        if (two && ok1 && ((keep1 >> lane) & 1ull))
            out[((size_t)b * NCELL + cell1) * 7 + 6] = 1.0f;
    }
}

extern "C" void kernel_launch(void* const* d_in, const int* in_sizes, int n_in,
                              void* d_out, int out_size, void* d_ws, size_t ws_size,
                              hipStream_t stream) {
    const float* feat = (const float*)d_in[0];
    const int* h_ori  = (const int*)d_in[1];
    const int* w_ori  = (const int*)d_in[2];
    float* out = (float*)d_out;

    yolo_fused<<<BATCH, 1024, 0, stream>>>(feat, h_ori, w_ori, out);
}

// Round 5
// 26.066 us; speedup vs baseline: 9.6734x; 1.2401x over previous
//
#include <hip/hip_runtime.h>

#define BATCH 64
#define CH 31
#define HF 28
#define WF 28
#define NCELL 784   // 28*28
#define NCLS 21
#define BGCLS 20
#define CAP 128     // per-class bucket capacity (P(n>128) ~ 1e-38)
#define NMS_THR 0.5f

__device__ __forceinline__ float bcast_f(float v, int l) {
    return __int_as_float(__builtin_amdgcn_readlane(__float_as_int(v), l));
}
__device__ __forceinline__ unsigned long long shfl_xor_u64(unsigned long long v, int j) {
    int lo = __shfl_xor((int)(unsigned)(v & 0xFFFFFFFFull), j, 64);
    int hi = __shfl_xor((int)(unsigned)(v >> 32), j, 64);
    return ((unsigned long long)(unsigned)hi << 32) | (unsigned)lo;
}

// compare-exchange with partner lane^J; UP=true -> ascending pair
#define CEX0(VAR, J, UP) { unsigned long long p_ = shfl_xor_u64(VAR, (J));     \
    bool tm_ = (((lane & (J)) == 0) == (UP));                                  \
    VAR = ((VAR < p_) == tm_) ? VAR : p_; }

// ---------------------------------------------------------------------------
// Kernel 1: per-cell decode. Writes output row, class-offset box (ws), and a
// sort tag: (~orderable(score))<<15 | cat<<10 | cell  (bg -> ~0ull).
// Ascending tag order == score desc, cell asc (stable argsort of -score).
// ---------------------------------------------------------------------------
__global__ __launch_bounds__(256)
void decode_kernel(const float* __restrict__ feat,
                   const int* __restrict__ hofp,
                   const int* __restrict__ wofp,
                   float* __restrict__ out,
                   float4* __restrict__ wbox,
                   unsigned long long* __restrict__ wkey)
{
    int gid = blockIdx.x * blockDim.x + threadIdx.x;
    if (gid >= BATCH * NCELL) return;
    int b = gid / NCELL;
    int n = gid - b * NCELL;

    const float* base = feat + (size_t)b * CH * NCELL + n;
    float x[CH];
#pragma unroll
    for (int c = 0; c < CH; ++c) x[c] = base[(size_t)c * NCELL];

    float c0 = x[4], c1 = x[9];
    int carg = (c1 > c0) ? 1 : 0;
    float cmax = fmaxf(c0, c1);

    float m = x[10];
#pragma unroll
    for (int k = 1; k < NCLS; ++k) m = fmaxf(m, x[10 + k]);
    float e[NCLS];
    float sum = 0.0f;
#pragma unroll
    for (int k = 0; k < NCLS; ++k) { e[k] = expf(x[10 + k] - m); sum += e[k]; }

    float best = -INFINITY;
    int cat = 0;
#pragma unroll
    for (int k = 0; k < NCLS; ++k) {
        float cp = cmax * (e[k] / sum);
        if (cp > best) { best = cp; cat = k; }
    }

    float rx = carg ? x[5] : x[0];
    float ry = carg ? x[6] : x[1];
    float rw = carg ? x[7] : x[2];
    float rh = carg ? x[8] : x[3];
    rx = 1.0f / (1.0f + expf(-rx));
    ry = 1.0f / (1.0f + expf(-ry));
    rw = 1.0f / (1.0f + expf(-rw));
    rh = 1.0f / (1.0f + expf(-rh));

    float w_ori = (float)(*wofp), h_ori = (float)(*hofp);
    float sw = w_ori / (float)WF, sh = h_ori / (float)HF;
    float col = (float)(n % WF), row = (float)(n / WF);
    float cx = (rx + col) * sw;
    float cy = (ry + row) * sh;
    float bw = rw * w_ori;
    float bh = rh * h_ori;
    float x1 = cx - bw * 0.5f, y1 = cy - bh * 0.5f;
    float x2 = cx + bw * 0.5f, y2 = cy + bh * 0.5f;

    float* o = out + (size_t)gid * 7;
    o[0] = x1; o[1] = y1; o[2] = x2; o[3] = y2;
    o[4] = best; o[5] = (float)cat; o[6] = 0.0f;

    float off = (float)cat * 4096.0f;   // keep offset: bitwise parity w/ ref
    wbox[gid] = make_float4(x1 + off, y1 + off, x2 + off, y2 + off);

    unsigned long long key = ~0ull;     // bg marker (cat field = 31)
    if (cat != BGCLS) {
        unsigned u = __float_as_uint(best);
        u = (u & 0x80000000u) ? ~u : (u | 0x80000000u);   // orderable asc
        key = ((unsigned long long)(~u) << 15) |
              ((unsigned long long)cat << 10) | (unsigned)n;
    }
    wkey[gid] = key;
}

// ---------------------------------------------------------------------------
// Kernel 2: one single-wave block per (image, class). Scan tags (L2-hot),
// ballot-compact into LDS, in-register bitonic sort, wave-synchronous greedy.
// ---------------------------------------------------------------------------
__global__ __launch_bounds__(64)
void nms_kernel(const float4* __restrict__ wbox,
                const unsigned long long* __restrict__ wkey,
                float* __restrict__ out)
{
    const int blk = blockIdx.x;
    const int b = blk / (NCLS - 1);
    const int c = blk - b * (NCLS - 1);
    const int lane = threadIdx.x;

    __shared__ unsigned long long lbuf[CAP];
    lbuf[lane] = ~0ull;
    lbuf[64 + lane] = ~0ull;

    // ---- compact this class's keys (ballot + prefix, no atomics) ----
    int base = 0;
    const unsigned long long* wk = wkey + (size_t)b * NCELL;
#pragma unroll
    for (int it = 0; it < 13; ++it) {
        int cell = it * 64 + lane;
        bool m2 = false;
        unsigned long long key = ~0ull;
        if (cell < NCELL) {
            key = wk[cell];
            m2 = (((key >> 10) & 31ull) == (unsigned long long)c);
        }
        unsigned long long bal = __ballot(m2);
        if (m2) {
            int pos = base + __popcll(bal & ((1ull << lane) - 1ull));
            if (pos < CAP) lbuf[pos] = key;
        }
        base += (int)__popcll(bal);
    }
    __syncthreads();
    int n = base > CAP ? CAP : base;
    if (n == 0) return;

    unsigned long long k0 = lbuf[lane];
    unsigned long long k1 = lbuf[64 + lane];
    bool two = (n > 64);

    if (!two) {
#pragma unroll
        for (int k = 2; k <= 64; k <<= 1) {
            bool up = ((lane & k) == 0);
#pragma unroll
            for (int j = k >> 1; j >= 1; j >>= 1) CEX0(k0, j, up)
        }
    } else {
#pragma unroll
        for (int k = 2; k <= 32; k <<= 1) {
            bool up = ((lane & k) == 0);
#pragma unroll
            for (int j = k >> 1; j >= 1; j >>= 1) { CEX0(k0, j, up) CEX0(k1, j, up) }
        }
#pragma unroll
        for (int j = 32; j >= 1; j >>= 1) { CEX0(k0, j, true) CEX0(k1, j, false) }
        {
            unsigned long long mn = (k0 < k1) ? k0 : k1;
            unsigned long long mx = (k0 < k1) ? k1 : k0;
            k0 = mn; k1 = mx;
        }
#pragma unroll
        for (int j = 32; j >= 1; j >>= 1) { CEX0(k0, j, true) CEX0(k1, j, true) }
    }

    int cell0 = (int)(k0 & 1023ull);
    int cell1 = (int)(k1 & 1023ull);
    bool ok0 = (lane < n);
    bool ok1 = (64 + lane) < n;

    const float4* wb = wbox + (size_t)b * NCELL;
    float4 B0 = wb[ok0 ? cell0 : 0];
    float a0 = fmaxf(B0.z - B0.x, 0.f) * fmaxf(B0.w - B0.y, 0.f);
    float4 B1 = make_float4(0.f, 0.f, 0.f, 0.f);
    float a1 = 0.f;
    if (two) {
        B1 = wb[ok1 ? cell1 : 0];
        a1 = fmaxf(B1.z - B1.x, 0.f) * fmaxf(B1.w - B1.y, 0.f);
    }

    unsigned long long keep0 = (n >= 64) ? ~0ull : ((1ull << n) - 1);
    unsigned long long keep1 = two ? ((n >= 128) ? ~0ull : ((1ull << (n - 64)) - 1))
                                   : 0ull;

    unsigned long long rem = keep0;
    while (rem) {
        int i = __builtin_ctzll(rem);
        rem &= rem - 1;
        float ix1 = bcast_f(B0.x, i), iy1 = bcast_f(B0.y, i);
        float ix2 = bcast_f(B0.z, i), iy2 = bcast_f(B0.w, i);
        float ia  = bcast_f(a0, i);
        {
            float xx1 = fmaxf(ix1, B0.x), yy1 = fmaxf(iy1, B0.y);
            float xx2 = fminf(ix2, B0.z), yy2 = fminf(iy2, B0.w);
            float inter = fmaxf(xx2 - xx1, 0.f) * fmaxf(yy2 - yy1, 0.f);
            float uni = ia + a0 - inter;
            bool s = (inter / fmaxf(uni, 1e-9f)) > NMS_THR;
            unsigned long long mm = __ballot(s) & keep0;
            mm &= (i < 63) ? (~0ull << (i + 1)) : 0ull;
            keep0 &= ~mm; rem &= ~mm;
        }
        if (two) {
            float xx1 = fmaxf(ix1, B1.x), yy1 = fmaxf(iy1, B1.y);
            float xx2 = fminf(ix2, B1.z), yy2 = fminf(iy2, B1.w);
            float inter = fmaxf(xx2 - xx1, 0.f) * fmaxf(yy2 - yy1, 0.f);
            float uni = ia + a1 - inter;
            bool s = (inter / fmaxf(uni, 1e-9f)) > NMS_THR;
            keep1 &= ~(__ballot(s) & keep1);
        }
    }
    if (two) {
        unsigned long long rem1 = keep1;
        while (rem1) {
            int i = __builtin_ctzll(rem1);
            rem1 &= rem1 - 1;
            float ix1 = bcast_f(B1.x, i), iy1 = bcast_f(B1.y, i);
            float ix2 = bcast_f(B1.z, i), iy2 = bcast_f(B1.w, i);
            float ia  = bcast_f(a1, i);
            float xx1 = fmaxf(ix1, B1.x), yy1 = fmaxf(iy1, B1.y);
            float xx2 = fminf(ix2, B1.z), yy2 = fminf(iy2, B1.w);
            float inter = fmaxf(xx2 - xx1, 0.f) * fmaxf(yy2 - yy1, 0.f);
            float uni = ia + a1 - inter;
            bool s = (inter / fmaxf(uni, 1e-9f)) > NMS_THR;
            unsigned long long mm = __ballot(s) & keep1;
            mm &= (i < 63) ? (~0ull << (i + 1)) : 0ull;
            keep1 &= ~mm; rem1 &= ~mm;
        }
    }

    if (ok0 && ((keep0 >> lane) & 1ull))
        out[((size_t)b * NCELL + cell0) * 7 + 6] = 1.0f;
    if (two && ok1 && ((keep1 >> lane) & 1ull))
        out[((size_t)b * NCELL + cell1) * 7 + 6] = 1.0f;
}

extern "C" void kernel_launch(void* const* d_in, const int* in_sizes, int n_in,
                              void* d_out, int out_size, void* d_ws, size_t ws_size,
                              hipStream_t stream) {
    const float* feat = (const float*)d_in[0];
    const int* h_ori  = (const int*)d_in[1];
    const int* w_ori  = (const int*)d_in[2];
    float* out = (float*)d_out;

    float4* wbox = (float4*)d_ws;
    unsigned long long* wkey =
        (unsigned long long*)((char*)d_ws + sizeof(float4) * BATCH * NCELL);

    int total = BATCH * NCELL;
    decode_kernel<<<(total + 255) / 256, 256, 0, stream>>>(
        feat, h_ori, w_ori, out, wbox, wkey);
    nms_kernel<<<BATCH * (NCLS - 1), 64, 0, stream>>>(wbox, wkey, out);
}